// Round 1
// baseline (469.325 us; speedup 1.0000x reference)
//
#include <hip/hip_runtime.h>

// SegmentedSmoothing: 5x5 clipped-window average where each pixel averages
// only same-class neighbors. Class = boundary band (within BW=10 of any edge)
// vs interior. Input/out: fp32 (4,16,720,1440).
//
// Structure: 95% of pixels ("pure" region i in [12,708), j in [12,1428)) have
// an unclipped all-interior window -> plain 25-box-sum / 25. Only a thin band
// needs the masked general path.

#define HH 720
#define WW 1440
#define PLANE (HH * WW)   // 1,036,800
#define NPLANES 64        // 4*16

// ---------------- fast kernel: pure-interior region ----------------
// Each thread computes 4 consecutive outputs (j0..j0+3) for 24 consecutive
// rows, with a rolling ring of 5 horizontal window-sums.
// j groups: j0 = 12 + 4*g, g in [0,354). row chunks: 29 chunks of 24 rows.

#define NG 354
#define NCHUNK 29
#define CHUNK 24

__device__ __forceinline__ float4 hsum5(const float* __restrict__ p) {
    // p points at element j0 (16B aligned). Need floats p[-2..5].
    const float2 l = *(const float2*)(p - 2);  // 8B aligned
    const float4 m = *(const float4*)(p);      // 16B aligned
    const float2 r = *(const float2*)(p + 4);  // 16B aligned
    float4 h;
    h.x = l.x + l.y + m.x + m.y + m.z;
    h.y = h.x - l.x + m.w;
    h.z = h.y - l.y + r.x;
    h.w = h.z - m.x + r.y;
    return h;
}

__global__ __launch_bounds__(256) void fast_kernel(const float* __restrict__ x,
                                                   float* __restrict__ out) {
    const int id = blockIdx.x * 256 + threadIdx.x;
    if (id >= NG * NCHUNK) return;
    const int chunk = id / NG;
    const int g     = id - chunk * NG;
    const int j0    = 12 + 4 * g;
    const int row0  = 12 + chunk * CHUNK;

    const float* __restrict__ xp = x + (size_t)blockIdx.y * PLANE;
    float* __restrict__ op       = out + (size_t)blockIdx.y * PLANE;

    float4 h[5];
    // prime rows row0-2 .. row0+1 into h[0..3]
#pragma unroll
    for (int t = 0; t < 4; ++t) {
        h[t] = hsum5(xp + (row0 - 2 + t) * WW + j0);
    }

#pragma unroll
    for (int t = 0; t < CHUNK; ++t) {
        const int r = row0 + t;
        h[(t + 4) % 5] = hsum5(xp + (r + 2) * WW + j0);
        float4 v;
        v.x = ((h[0].x + h[1].x) + (h[2].x + h[3].x)) + h[4].x;
        v.y = ((h[0].y + h[1].y) + (h[2].y + h[3].y)) + h[4].y;
        v.z = ((h[0].z + h[1].z) + (h[2].z + h[3].z)) + h[4].z;
        v.w = ((h[0].w + h[1].w) + (h[2].w + h[3].w)) + h[4].w;
        const float s = 1.0f / 25.0f;
        v.x *= s; v.y *= s; v.z *= s; v.w *= s;
        *(float4*)(op + r * WW + j0) = v;
    }
}

// ---------------- edge kernel: complex band ----------------
// Complex pixels per plane: rows {0..11, 708..719} full width (24*1440=34560)
// plus rows 12..707 with j in {0..11, 1428..1439} (696*24=16704). Total 51264.

#define NEDGE 51264

__global__ __launch_bounds__(256) void edge_kernel(const float* __restrict__ x,
                                                   float* __restrict__ out) {
    const int p = blockIdx.x * 256 + threadIdx.x;
    if (p >= NEDGE) return;
    int i, j;
    if (p < 34560) {
        i = p / 1440;
        j = p - i * 1440;
        if (i >= 12) i += 696;   // 12..23 -> 708..719
    } else {
        const int q  = p - 34560;
        const int qi = q / 24;
        const int r  = q - qi * 24;
        i = 12 + qi;
        j = (r < 12) ? r : r + 1416;  // 1428..1439
    }

    const float* __restrict__ xp = x + (size_t)blockIdx.y * PLANE;
    const bool cb = (i < 10) | (i >= 710) | (j < 10) | (j >= 1430);

    float s = 0.0f, cnt = 0.0f;
#pragma unroll
    for (int di = -2; di <= 2; ++di) {
#pragma unroll
        for (int dj = -2; dj <= 2; ++dj) {
            const int ni = i + di, nj = j + dj;
            const bool inb = ((unsigned)ni < (unsigned)HH) & ((unsigned)nj < (unsigned)WW);
            const bool nb  = (ni < 10) | (ni >= 710) | (nj < 10) | (nj >= 1430);
            const int ci = min(max(ni, 0), HH - 1);
            const int cj = min(max(nj, 0), WW - 1);
            const float v = xp[ci * WW + cj];
            const float w = (inb && (nb == cb)) ? 1.0f : 0.0f;
            s += w * v;
            cnt += w;
        }
    }
    out[(size_t)blockIdx.y * PLANE + i * WW + j] = s / cnt;
}

extern "C" void kernel_launch(void* const* d_in, const int* in_sizes, int n_in,
                              void* d_out, int out_size, void* d_ws, size_t ws_size,
                              hipStream_t stream) {
    const float* x = (const float*)d_in[0];
    float* out = (float*)d_out;

    // fast: 354 groups * 29 chunks = 10266 threads/plane -> 41 blocks of 256
    dim3 gf((NG * NCHUNK + 255) / 256, NPLANES);
    hipLaunchKernelGGL(fast_kernel, gf, dim3(256), 0, stream, x, out);

    // edge: 51264 threads/plane -> 201 blocks of 256
    dim3 ge((NEDGE + 255) / 256, NPLANES);
    hipLaunchKernelGGL(edge_kernel, ge, dim3(256), 0, stream, x, out);
}